// Round 17
// baseline (32.279 us; speedup 1.0000x reference)
//
#include <hip/hip_runtime.h>

#define C_IN   8
#define CH     8
#define Hh     128
#define Ww     192
#define HW     (Hh*Ww)
#define NINST  128
#define NPAR   169
#define OH     256
#define OW     384
#define B      4             // owned source rows per block
#define RT     (B+1)         // computed rows incl. bottom halo
#define NRG    (Hh/B)        // 32 row groups

typedef float f32x2 __attribute__((ext_vector_type(2)));
typedef float f32x4 __attribute__((ext_vector_type(4)));

__device__ __forceinline__ f32x2 pk2(float s) { f32x2 r; r.x = s; r.y = s; return r; }

// Packed LDS weights (16B-aligned, 192 floats) — R11/R14 proven layout:
//   [0,96): w0 [8][12] | [96,160): w1 [8][8] | [160,168): w2[8]
//   [168,176): b0 | [176,184): b1 | [184]: b2
//
// Output mapping (verified R3-R16): block rg computes source rows [r0, r0+4],
// writes out rows [2r0+2, 2r0+10); rg==0 adds {0,1}; rg==31 clips 256,257.
//
// Codegen lessons: VGPR bins (m69): <=64 -> 8 waves/SIMD, 65-128 -> 4.
// w=3 builds sit at 76-84 VGPR (4-wave bin). Prior <=64 attempts spilled
// because of cross-phase register state (R6/R7/R13/R15). R17: one row-PAIR
// per phase, logits straight to LDS -> per-phase live ~50 VGPR, zero state
// across fences. Target: VGPR<=64, no spill, 8 waves/SIMD.

__global__ __launch_bounds__(192, 4)
void fused_maskhead_kernel(const float* __restrict__ feats,
                           const float* __restrict__ params,
                           const float* __restrict__ locs,
                           const int* __restrict__ im_inds,
                           const int* __restrict__ fpn,
                           float* __restrict__ out)
{
    __shared__ __align__(16) float sw[192];
    __shared__ float sl[RT][Ww];    // 5*192*4 = 3840 B

    const int rg   = blockIdx.x;    // 0..31
    const int inst = blockIdx.y;    // 0..127
    const int x    = threadIdx.x;   // 0..191 — one column per thread
    const int r0   = rg * B;        // <= 124: rows r0..r0+3 never clamp

    // stage + repack params (coalesced global read, remapped LDS write)
    if (x < NPAR) {
        const int r = x;
        int dst;
        if (r < 80)       { const int o = r / 10; dst = o * 12 + (r - o * 10); }
        else if (r < 144) dst = 96  + (r - 80);
        else if (r < 152) dst = 160 + (r - 144);
        else if (r < 160) dst = 168 + (r - 152);
        else if (r < 168) dst = 176 + (r - 160);
        else              dst = 184;
        sw[dst] = params[inst * NPAR + r];
    }

    const float ixv = locs[inst * 2 + 0];
    const float iyv = locs[inst * 2 + 1];
    const float inv_soi = 1.0f / (float)(64 << fpn[inst]);
    const float rx = (ixv - (float)(x * 8 + 4)) * inv_soi;
    const float* fb = feats + (size_t)im_inds[inst] * (C_IN * HW) + x;

    __syncthreads();

    // One row-pair {ra, rb} -> logits into sl[i0], sl[i1] (i1<0: discard .y).
    // Per-phase live set ~50 VGPR: f2[8]+h1[8] pairs + base scalars.
    auto mlp2 = [&](int ra, int rb, int i0, int i1) {
        f32x2 ry;
        ry.x = (iyv - (float)(ra * 8 + 4)) * inv_soi;
        ry.y = (iyv - (float)(rb * 8 + 4)) * inv_soi;

        f32x2 f2[C_IN];
        #pragma unroll
        for (int c = 0; c < C_IN; ++c) {
            const float* fc = fb + c * HW;
            f2[c].x = fc[ra * Ww];
            f2[c].y = fc[rb * Ww];
        }

        f32x2 h1[CH];
        #pragma unroll
        for (int o = 0; o < CH; ++o) {
            const f32x4 wa = *(const f32x4*)(sw + o * 12 + 0);
            const f32x4 wb = *(const f32x4*)(sw + o * 12 + 4);
            const f32x4 wc = *(const f32x4*)(sw + o * 12 + 8);   // .z/.w pad
            const float c0 = fmaf(wa.x, rx, sw[168 + o]);
            f32x2 a = pk2(wa.y) * ry + pk2(c0);
            a = pk2(wa.z) * f2[0] + a;
            a = pk2(wa.w) * f2[1] + a;
            a = pk2(wb.x) * f2[2] + a;
            a = pk2(wb.y) * f2[3] + a;
            a = pk2(wb.z) * f2[4] + a;
            a = pk2(wb.w) * f2[5] + a;
            a = pk2(wc.x) * f2[6] + a;
            a = pk2(wc.y) * f2[7] + a;
            h1[o].x = fmaxf(a.x, 0.0f);
            h1[o].y = fmaxf(a.y, 0.0f);
        }

        f32x2 z = pk2(sw[184]);
        #pragma unroll
        for (int o = 0; o < CH; ++o) {
            const f32x4 wa = *(const f32x4*)(sw + 96 + o * 8 + 0);
            const f32x4 wb = *(const f32x4*)(sw + 96 + o * 8 + 4);
            f32x2 a = pk2(sw[176 + o]);
            a = pk2(wa.x) * h1[0] + a;
            a = pk2(wa.y) * h1[1] + a;
            a = pk2(wa.z) * h1[2] + a;
            a = pk2(wa.w) * h1[3] + a;
            a = pk2(wb.x) * h1[4] + a;
            a = pk2(wb.y) * h1[5] + a;
            a = pk2(wb.z) * h1[6] + a;
            a = pk2(wb.w) * h1[7] + a;
            f32x2 t;
            t.x = fmaxf(a.x, 0.0f);
            t.y = fmaxf(a.y, 0.0f);
            z = pk2(sw[160 + o]) * t + z;          // layer-3 fold
        }
        sl[i0][x] = z.x;
        if (i1 >= 0) sl[i1][x] = z.y;
    };

    mlp2(r0 + 0, r0 + 1, 0, 1);
    asm volatile("" ::: "memory");      // phase boundary: no load hoisting
    mlp2(r0 + 2, r0 + 3, 2, 3);
    asm volatile("" ::: "memory");
    const int r4 = min(r0 + 4, Hh - 1);
    mlp2(r4, r4, 4, -1);                // halo row; .y discarded

    __syncthreads();

    // ---- 2x aligned bilinear from LDS tile (R9-proven epilogue)
    f32x2* outf2 = (f32x2*)out;
    const int xm1 = max(x - 1, 0);
    const int jlo = (rg == 0) ? -2 : 0;
    const int jhi = (rg == NRG - 1) ? 2 * B - 2 : 2 * B;

    #pragma unroll 4
    for (int jj = jlo; jj < jhi; ++jj) {
        const int oy  = 2 * r0 + 2 + jj;
        const int ay  = max(oy - 1, 0);
        const int y0l = (ay >> 1) - r0;            // 0..B
        const int y1l = min(y0l + 1, B);           // clamp only when fy==0
        const float fy = (ay & 1) ? 0.5f : 0.0f;

        const float t01 = sl[y0l][x];
        const float t00 = sl[y0l][xm1];
        const float t11 = sl[y1l][x];
        const float t10 = sl[y1l][xm1];

        const float rma = fmaf(fy, t10 - t00, t00);
        const float rmb = fmaf(fy, t11 - t01, t01);

        f32x2 v;
        v.x = 0.5f * (rma + rmb);
        v.y = rmb;
        outf2[((size_t)inst * OH + oy) * (OW / 2) + x] = v;
    }
}

extern "C" void kernel_launch(void* const* d_in, const int* in_sizes, int n_in,
                              void* d_out, int out_size, void* d_ws, size_t ws_size,
                              hipStream_t stream) {
    const float* feats  = (const float*)d_in[0];
    const float* params = (const float*)d_in[1];
    const float* locs   = (const float*)d_in[2];
    const int*   im     = (const int*)d_in[3];
    const int*   fpn    = (const int*)d_in[4];
    float* out = (float*)d_out;

    dim3 grid(NRG, NINST);   // 32 x 128 = 4096 blocks
    fused_maskhead_kernel<<<grid, 192, 0, stream>>>(feats, params, locs, im, fpn, out);
}

// Round 18
// 25.638 us; speedup vs baseline: 1.2590x; 1.2590x over previous
//
#include <hip/hip_runtime.h>

#define C_IN   8
#define CH     8
#define Hh     128
#define Ww     192
#define HW     (Hh*Ww)
#define NINST  128
#define NPAR   169
#define OH     256
#define OW     384
#define B      4             // owned source rows per block
#define NRG    (Hh/B)        // 32 row groups

typedef float f32x2 __attribute__((ext_vector_type(2)));
typedef float f32x4 __attribute__((ext_vector_type(4)));

__device__ __forceinline__ f32x2 pk2(float s) { f32x2 r; r.x = s; r.y = s; return r; }
__device__ __forceinline__ f32x2 relu2(f32x2 a) {
    return __builtin_elementwise_max(a, (f32x2)0.0f);   // v_pk_max_f32
}

// Packed LDS weights (16B-aligned, 192 floats) — R11/R14 proven layout:
//   [0,96): w0 [8][12] | [96,160): w1 [8][8] | [160,168): w2[8]
//   [168,176): b0 | [176,184): b1 | [184]: b2
//
// Output mapping (verified R3-R17): block rg computes source rows [r0, r0+4],
// writes out rows [2r0+2, 2r0+10); rg==0 adds {0,1}; rg==31 clips 256,257.
//
// Final structure (R18 = R14 + pk-relu + nt-stores + grid swap). Ledger:
// not VALU-issue-bound (R11), not LDS-bound (R14), not occupancy-bound (R17),
// grid 4096 optimal (R9 vs R16), w=3 the only spill-free point (R6-R8,R13,R15).

__global__ __launch_bounds__(192, 3)
void fused_maskhead_kernel(const float* __restrict__ feats,
                           const float* __restrict__ params,
                           const float* __restrict__ locs,
                           const int* __restrict__ im_inds,
                           const int* __restrict__ fpn,
                           float* __restrict__ out)
{
    __shared__ __align__(16) float sw[192];
    __shared__ float sb[2][5];      // boundary z for cols 63, 127

    const int inst = blockIdx.x;    // 0..127  (swapped: consecutive blocks
    const int rg   = blockIdx.y;    // 0..31    share feat rows, differ in inst)
    const int x    = threadIdx.x;   // 0..191 — one column per thread
    const int r0   = rg * B;        // <= 124: rows r0..r0+3 never clamp

    // stage + repack params (coalesced global read, remapped LDS write)
    if (x < NPAR) {
        const int r = x;
        int dst;
        if (r < 80)       { const int o = r / 10; dst = o * 12 + (r - o * 10); }
        else if (r < 144) dst = 96  + (r - 80);
        else if (r < 152) dst = 160 + (r - 144);
        else if (r < 160) dst = 168 + (r - 152);
        else if (r < 168) dst = 176 + (r - 160);
        else              dst = 184;
        sw[dst] = params[inst * NPAR + r];
    }

    const float ixv = locs[inst * 2 + 0];
    const float iyv = locs[inst * 2 + 1];
    const float inv_soi = 1.0f / (float)(64 << fpn[inst]);
    const float rx = (ixv - (float)(x * 8 + 4)) * inv_soi;
    const float* fb = feats + (size_t)im_inds[inst] * (C_IN * HW) + x;
    const int sr4 = min(r0 + 4, Hh - 1);

    // rows paired {0,1},{2,3}; halo row 4 scalar
    f32x2 ry2[2];
    ry2[0].x = (iyv - (float)((r0 + 0) * 8 + 4)) * inv_soi;
    ry2[0].y = (iyv - (float)((r0 + 1) * 8 + 4)) * inv_soi;
    ry2[1].x = (iyv - (float)((r0 + 2) * 8 + 4)) * inv_soi;
    ry2[1].y = (iyv - (float)((r0 + 3) * 8 + 4)) * inv_soi;
    const float ry4 = (iyv - (float)(sr4 * 8 + 4)) * inv_soi;

    // feats issued before the staging barrier (latency overlaps)
    f32x2 f2[2][C_IN];
    float f4[C_IN];
    #pragma unroll
    for (int c = 0; c < C_IN; ++c) {
        const float* fc = fb + c * HW;
        f2[0][c].x = fc[(r0 + 0) * Ww];
        f2[0][c].y = fc[(r0 + 1) * Ww];
        f2[1][c].x = fc[(r0 + 2) * Ww];
        f2[1][c].y = fc[(r0 + 3) * Ww];
        f4[c]      = fc[sr4 * Ww];
    }

    __syncthreads();

    // ---- layer 1 (10 -> 8), pk-paired rows
    f32x2 h1a[CH], h1b[CH];
    float h1s[CH];
    #pragma unroll
    for (int o = 0; o < CH; ++o) {
        const f32x4 wa = *(const f32x4*)(sw + o * 12 + 0);
        const f32x4 wb = *(const f32x4*)(sw + o * 12 + 4);
        const f32x4 wc = *(const f32x4*)(sw + o * 12 + 8);   // .z/.w pad
        const float c0 = fmaf(wa.x, rx, sw[168 + o]);        // rx term hoisted
        const float wv[C_IN] = {wa.z, wa.w, wb.x, wb.y, wb.z, wb.w, wc.x, wc.y};

        f32x2 a0 = pk2(wa.y) * ry2[0] + pk2(c0);
        f32x2 a1 = pk2(wa.y) * ry2[1] + pk2(c0);
        float a4 = fmaf(wa.y, ry4, c0);
        #pragma unroll
        for (int c = 0; c < C_IN; ++c) {
            a0 = pk2(wv[c]) * f2[0][c] + a0;
            a1 = pk2(wv[c]) * f2[1][c] + a1;
            a4 = fmaf(wv[c], f4[c], a4);
        }
        h1a[o] = relu2(a0);
        h1b[o] = relu2(a1);
        h1s[o] = fmaxf(a4, 0.0f);
    }

    // ---- layer 2 + layer 3 fused (no h2 arrays)
    f32x2 z01 = pk2(sw[184]);
    f32x2 z23 = pk2(sw[184]);
    float z4v = sw[184];
    #pragma unroll
    for (int o = 0; o < CH; ++o) {
        const f32x4 wa = *(const f32x4*)(sw + 96 + o * 8 + 0);
        const f32x4 wb = *(const f32x4*)(sw + 96 + o * 8 + 4);
        const float bo = sw[176 + o];
        const float w2o = sw[160 + o];
        const float wv[CH] = {wa.x, wa.y, wa.z, wa.w, wb.x, wb.y, wb.z, wb.w};

        f32x2 a0 = pk2(bo);
        f32x2 a1 = pk2(bo);
        float a4 = bo;
        #pragma unroll
        for (int c = 0; c < CH; ++c) {
            a0 = pk2(wv[c]) * h1a[c] + a0;
            a1 = pk2(wv[c]) * h1b[c] + a1;
            a4 = fmaf(wv[c], h1s[c], a4);
        }
        z01 = pk2(w2o) * relu2(a0) + z01;
        z23 = pk2(w2o) * relu2(a1) + z23;
        z4v = fmaf(w2o, fmaxf(a4, 0.0f), z4v);
    }

    const float z0 = z01.x, z1 = z01.y, z2 = z23.x, z3 = z23.y, z4 = z4v;

    // boundary cols for the cross-wave shuffle (cols 64,128 need 63,127)
    if (x == 63)  { sb[0][0]=z0; sb[0][1]=z1; sb[0][2]=z2; sb[0][3]=z3; sb[0][4]=z4; }
    if (x == 127) { sb[1][0]=z0; sb[1][1]=z1; sb[1][2]=z2; sb[1][3]=z3; sb[1][4]=z4; }
    __syncthreads();

    float zp0 = __shfl_up(z0, 1);      // lane 0 keeps own value == col-0 clamp
    float zp1 = __shfl_up(z1, 1);
    float zp2 = __shfl_up(z2, 1);
    float zp3 = __shfl_up(z3, 1);
    float zp4 = __shfl_up(z4, 1);
    if (x == 64)  { zp0=sb[0][0]; zp1=sb[0][1]; zp2=sb[0][2]; zp3=sb[0][3]; zp4=sb[0][4]; }
    if (x == 128) { zp0=sb[1][0]; zp1=sb[1][1]; zp2=sb[1][2]; zp3=sb[1][3]; zp4=sb[1][4]; }

    // rm values for out rows oy=2r0+2+j (ay=2r0+1+j), j=0..7  (verified R13/R14)
    const float rmb[8] = { 0.5f*(z0+z1), z1, 0.5f*(z1+z2), z2,
                           0.5f*(z2+z3), z3, 0.5f*(z3+z4), z4 };
    const float rma[8] = { 0.5f*(zp0+zp1), zp1, 0.5f*(zp1+zp2), zp2,
                           0.5f*(zp2+zp3), zp3, 0.5f*(zp3+zp4), zp4 };

    f32x2* outf2 = (f32x2*)out;
    const size_t obase = ((size_t)inst * OH + (2 * r0 + 2)) * (OW / 2) + x;
    #pragma unroll
    for (int j = 0; j < 8; ++j) {
        if (rg < NRG - 1 || j < 6) {   // rg==31 clips rows 256,257
            f32x2 v;
            v.x = 0.5f * (rma[j] + rmb[j]);
            v.y = rmb[j];
            __builtin_nontemporal_store(v, &outf2[obase + (size_t)j * (OW / 2)]);
        }
    }
    if (rg == 0) {                     // out rows 0,1 (row-mix at ay=0)
        f32x2 v;
        v.x = 0.5f * (zp0 + z0);
        v.y = z0;
        const size_t e = (size_t)inst * OH * (OW / 2) + x;
        __builtin_nontemporal_store(v, &outf2[e]);
        __builtin_nontemporal_store(v, &outf2[e + (OW / 2)]);
    }
}

extern "C" void kernel_launch(void* const* d_in, const int* in_sizes, int n_in,
                              void* d_out, int out_size, void* d_ws, size_t ws_size,
                              hipStream_t stream) {
    const float* feats  = (const float*)d_in[0];
    const float* params = (const float*)d_in[1];
    const float* locs   = (const float*)d_in[2];
    const int*   im     = (const int*)d_in[3];
    const int*   fpn    = (const int*)d_in[4];
    float* out = (float*)d_out;

    dim3 grid(NINST, NRG);   // 128 x 32 = 4096 blocks (inst-major dispatch)
    fused_maskhead_kernel<<<grid, 192, 0, stream>>>(feats, params, locs, im, fpn, out);
}